// Round 2
// baseline (348.132 us; speedup 1.0000x reference)
//
#include <hip/hip_runtime.h>
#include <hip/hip_bf16.h>
#include <stdint.h>

#define D_MODEL 1024
#define NH 16
#define DK 64
#define SEQ 2048
#define BATCH 2
#define NTOK (BATCH * SEQ)  // 4096

typedef __bf16 bf16;
typedef float f32x4 __attribute__((ext_vector_type(4)));
typedef __bf16 bf16x8 __attribute__((ext_vector_type(8)));
typedef __bf16 bf16x4 __attribute__((ext_vector_type(4)));

__device__ __forceinline__ void gload_lds16(const void* g, void* l) {
  __builtin_amdgcn_global_load_lds(
      (const __attribute__((address_space(1))) void*)g,
      (__attribute__((address_space(3))) void*)l, 16, 0, 0);
}

// ---------------- prep kernels ----------------

__global__ void cast_x_kernel(const float* __restrict__ x, bf16* __restrict__ xb) {
  int i = blockIdx.x * 256 + threadIdx.x;
  float4 v = reinterpret_cast<const float4*>(x)[i];
  bf16x4 o;
  o[0] = (bf16)v.x; o[1] = (bf16)v.y; o[2] = (bf16)v.z; o[3] = (bf16)v.w;
  reinterpret_cast<bf16x4*>(xb)[i] = o;
}

// wt[j][k] = w_sel[k][j%1024], rows: [0,1024)=wq [1024,2048)=wk [2048,3072)=wv [3072,4096)=wo
__global__ void transpose_w_kernel(const float* __restrict__ wq, const float* __restrict__ wk,
                                   const float* __restrict__ wv, const float* __restrict__ wo,
                                   bf16* __restrict__ wt) {
  __shared__ float tile[32][33];
  const int jt = blockIdx.x;  // 0..127
  const int kt = blockIdx.y;  // 0..31
  const int tx = threadIdx.x & 31, ty = threadIdx.x >> 5;  // 32 x 8
  const int j0 = jt * 32;
  const int sel = j0 >> 10;
  const float* w = (sel == 0) ? wq : (sel == 1) ? wk : (sel == 2) ? wv : wo;
  const int jj0 = j0 & 1023;
#pragma unroll
  for (int i = 0; i < 4; ++i)
    tile[ty + i * 8][tx] = w[(size_t)(kt * 32 + ty + i * 8) * 1024 + jj0 + tx];
  __syncthreads();
#pragma unroll
  for (int i = 0; i < 4; ++i)
    wt[(size_t)(j0 + ty + i * 8) * 1024 + kt * 32 + tx] = (bf16)tile[tx][ty + i * 8];
}

__global__ void pack_mask_kernel(const int* __restrict__ mask, unsigned long long* __restrict__ bits) {
  int gt = blockIdx.x * 256 + threadIdx.x;
  int wid = gt >> 6;
  int l = gt & 63;
  int m = mask[(size_t)wid * 64 + l];
  unsigned long long b = __ballot(m != 0);
  if (l == 0) bits[wid] = b;
}

// ---------------- GEMM: C = A (MxK) * Bt^T (Bt is NxK row-major) ----------------
// MODE 0: QKV epilogue (writes q/k token-major bf16, v transposed per-head bf16)
// MODE 1: f32 output + bias
template <int MODE>
__global__ __launch_bounds__(256) void gemm_bt(
    const bf16* __restrict__ A, const bf16* __restrict__ Bt,
    const float* __restrict__ b0, const float* __restrict__ b1, const float* __restrict__ b2,
    bf16* __restrict__ out_q, bf16* __restrict__ out_k, bf16* __restrict__ out_vt,
    float* __restrict__ out_f) {
  __shared__ __align__(16) bf16 As[128 * 32];
  __shared__ __align__(16) bf16 Bs[128 * 32];
  const int tid = threadIdx.x;
  const int w = tid >> 6, l = tid & 63;
  const int wr = w >> 1, wc = w & 1;
  const int m0 = blockIdx.y * 128, n0 = blockIdx.x * 128;
  f32x4 acc[4][4] = {};
  const int lrow = l >> 2;       // 0..15
  const int lc8 = (l & 3) * 8;   // element col of the 16B chunk
  char* AsB = (char*)As;
  char* BsB = (char*)Bs;

  for (int k0 = 0; k0 < 1024; k0 += 32) {
#pragma unroll
    for (int is = 0; is < 2; ++is) {
      int arow = m0 + is * 64 + w * 16 + lrow;
      gload_lds16(A + (size_t)arow * 1024 + k0 + lc8, AsB + is * 4096 + w * 1024);
      int brow = n0 + is * 64 + w * 16 + lrow;
      gload_lds16(Bt + (size_t)brow * 1024 + k0 + lc8, BsB + is * 4096 + w * 1024);
    }
    __syncthreads();
    bf16x8 af[4], bfr[4];
#pragma unroll
    for (int m = 0; m < 4; ++m)
      af[m] = *reinterpret_cast<const bf16x8*>(As + (wr * 64 + m * 16 + (l & 15)) * 32 + (l >> 4) * 8);
#pragma unroll
    for (int n = 0; n < 4; ++n)
      bfr[n] = *reinterpret_cast<const bf16x8*>(Bs + (wc * 64 + n * 16 + (l & 15)) * 32 + (l >> 4) * 8);
#pragma unroll
    for (int m = 0; m < 4; ++m)
#pragma unroll
      for (int n = 0; n < 4; ++n)
        acc[m][n] = __builtin_amdgcn_mfma_f32_16x16x32_bf16(af[m], bfr[n], acc[m][n], 0, 0, 0);
    __syncthreads();
  }

#pragma unroll
  for (int m = 0; m < 4; ++m) {
    int ib = m0 + wr * 64 + m * 16 + 4 * (l >> 4);
#pragma unroll
    for (int n = 0; n < 4; ++n) {
      int j = n0 + wc * 64 + n * 16 + (l & 15);
      if (MODE == 1) {
        float bias = b0[j];
#pragma unroll
        for (int r = 0; r < 4; ++r)
          out_f[(size_t)(ib + r) * 1024 + j] = acc[m][n][r] + bias;
      } else {
        int sel = j >> 10, jj = j & 1023;
        const float* bp = (sel == 0) ? b0 : (sel == 1) ? b1 : b2;
        float bias = bp[jj];
        if (sel < 2) {
          bf16* dst = (sel == 0) ? out_q : out_k;
#pragma unroll
          for (int r = 0; r < 4; ++r)
            dst[(size_t)(ib + r) * 1024 + jj] = (bf16)(acc[m][n][r] + bias);
        } else {
          int hh = jj >> 6, dd = jj & 63;
          int bb = ib >> 11, ss = ib & 2047;
          bf16x4 v;
#pragma unroll
          for (int r = 0; r < 4; ++r) v[r] = (bf16)(acc[m][n][r] + bias);
          *reinterpret_cast<bf16x4*>(out_vt + ((size_t)(bb * NH + hh) * DK + dd) * SEQ + ss) = v;
        }
      }
    }
  }
}

// ---------------- flash attention ----------------
// grid: (16 q-tiles, NH, BATCH), block 256 (4 waves x 32 q-rows)
__global__ __launch_bounds__(256) void attn_kernel(
    const bf16* __restrict__ qb, const bf16* __restrict__ kb,
    const bf16* __restrict__ vt, const unsigned long long* __restrict__ mbits,
    bf16* __restrict__ ob) {
  __shared__ __align__(16) bf16 Ks[64 * 64];       // [key][d]
  __shared__ __align__(16) bf16 Vs[64 * 64];       // [d][key]
  __shared__ __align__(16) bf16 Ps[4][32 * 64];    // per-wave [q][key]
  const int tid = threadIdx.x;
  const int w = tid >> 6, l = tid & 63;
  const int qt = blockIdx.x, h = blockIdx.y, b = blockIdx.z;
  const int q0 = qt * 128 + w * 32;
  const int tok0 = b * SEQ + q0;

  // Q fragments in registers: [m][kk]
  bf16x8 qf[2][2];
#pragma unroll
  for (int m = 0; m < 2; ++m)
#pragma unroll
    for (int kk = 0; kk < 2; ++kk)
      qf[m][kk] = *reinterpret_cast<const bf16x8*>(
          qb + (size_t)(tok0 + m * 16 + (l & 15)) * 1024 + h * 64 + kk * 32 + (l >> 4) * 8);

  float mprev[2][4], lsum[2][4];
  f32x4 oacc[2][4] = {};
#pragma unroll
  for (int m = 0; m < 2; ++m)
#pragma unroll
    for (int r = 0; r < 4; ++r) { mprev[m][r] = -INFINITY; lsum[m][r] = 0.f; }

  char* KsB = (char*)Ks;
  char* VsB = (char*)Vs;
  const int srow = l >> 3;          // 0..7
  const int scol = (l & 7) * 8;     // element col of 16B chunk

  for (int kt = 0; kt < 32; ++kt) {
#pragma unroll
    for (int is = 0; is < 2; ++is) {
      int row = is * 32 + w * 8 + srow;
      gload_lds16(kb + (size_t)(b * SEQ + kt * 64 + row) * 1024 + h * 64 + scol,
                  KsB + is * 4096 + w * 1024);
      gload_lds16(vt + ((size_t)(b * NH + h) * DK + row) * SEQ + kt * 64 + scol,
                  VsB + is * 4096 + w * 1024);
    }
    __syncthreads();

    // S = Q K^T (per wave: 32 q x 64 keys)
    f32x4 sa[2][4] = {};
#pragma unroll
    for (int kk = 0; kk < 2; ++kk) {
      bf16x8 kf[4];
#pragma unroll
      for (int n = 0; n < 4; ++n)
        kf[n] = *reinterpret_cast<const bf16x8*>(Ks + (n * 16 + (l & 15)) * 64 + kk * 32 + (l >> 4) * 8);
#pragma unroll
      for (int m = 0; m < 2; ++m)
#pragma unroll
        for (int n = 0; n < 4; ++n)
          sa[m][n] = __builtin_amdgcn_mfma_f32_16x16x32_bf16(qf[m][kk], kf[n], sa[m][n], 0, 0, 0);
    }

    // masked online softmax per q-row
#pragma unroll
    for (int m = 0; m < 2; ++m) {
#pragma unroll
      for (int r = 0; r < 4; ++r) {
        int qg = q0 + m * 16 + 4 * (l >> 4) + r;
        unsigned long long mw = mbits[(size_t)(b * SEQ + qg) * 32 + kt];
        float sv[4];
        float mx = -1e30f;
#pragma unroll
        for (int n = 0; n < 4; ++n) {
          float s = sa[m][n][r] * 0.125f;
          if (!((mw >> (n * 16 + (l & 15))) & 1ull)) s = -1e9f;
          sv[n] = s;
          mx = fmaxf(mx, s);
        }
        mx = fmaxf(mx, __shfl_xor(mx, 1));
        mx = fmaxf(mx, __shfl_xor(mx, 2));
        mx = fmaxf(mx, __shfl_xor(mx, 4));
        mx = fmaxf(mx, __shfl_xor(mx, 8));
        float mnew = fmaxf(mprev[m][r], mx);
        float psum = 0.f;
#pragma unroll
        for (int n = 0; n < 4; ++n) {
          float p = __expf(sv[n] - mnew);
          psum += p;
          Ps[w][(m * 16 + 4 * (l >> 4) + r) * 64 + n * 16 + (l & 15)] = (bf16)p;
        }
        psum += __shfl_xor(psum, 1);
        psum += __shfl_xor(psum, 2);
        psum += __shfl_xor(psum, 4);
        psum += __shfl_xor(psum, 8);
        float alpha = __expf(mprev[m][r] - mnew);
        mprev[m][r] = mnew;
        lsum[m][r] = lsum[m][r] * alpha + psum;
#pragma unroll
        for (int dn = 0; dn < 4; ++dn) oacc[m][dn][r] *= alpha;
      }
    }

    // O += P * V
#pragma unroll
    for (int kk = 0; kk < 2; ++kk) {
      bf16x8 pa[2], vf[4];
#pragma unroll
      for (int m = 0; m < 2; ++m)
        pa[m] = *reinterpret_cast<const bf16x8*>(Ps[w] + (m * 16 + (l & 15)) * 64 + kk * 32 + (l >> 4) * 8);
#pragma unroll
      for (int dn = 0; dn < 4; ++dn)
        vf[dn] = *reinterpret_cast<const bf16x8*>(Vs + (dn * 16 + (l & 15)) * 64 + kk * 32 + (l >> 4) * 8);
#pragma unroll
      for (int m = 0; m < 2; ++m)
#pragma unroll
        for (int dn = 0; dn < 4; ++dn)
          oacc[m][dn] = __builtin_amdgcn_mfma_f32_16x16x32_bf16(pa[m], vf[dn], oacc[m][dn], 0, 0, 0);
    }
    __syncthreads();
  }

  // epilogue: normalize and store bf16 token-major
#pragma unroll
  for (int m = 0; m < 2; ++m)
#pragma unroll
    for (int r = 0; r < 4; ++r) {
      float inv = 1.f / lsum[m][r];
      int tok = tok0 + m * 16 + 4 * (l >> 4) + r;
#pragma unroll
      for (int dn = 0; dn < 4; ++dn)
        ob[(size_t)tok * 1024 + h * 64 + dn * 16 + (l & 15)] = (bf16)(oacc[m][dn][r] * inv);
    }
}

// ---------------- launch ----------------
extern "C" void kernel_launch(void* const* d_in, const int* in_sizes, int n_in,
                              void* d_out, int out_size, void* d_ws, size_t ws_size,
                              hipStream_t stream) {
  const float* x = (const float*)d_in[0];
  const int* mask = (const int*)d_in[1];
  const float* wq = (const float*)d_in[2];
  const float* bq = (const float*)d_in[3];
  const float* wk = (const float*)d_in[4];
  const float* bk = (const float*)d_in[5];
  const float* wv = (const float*)d_in[6];
  const float* bv = (const float*)d_in[7];
  const float* wo = (const float*)d_in[8];
  const float* bo = (const float*)d_in[9];
  float* out = (float*)d_out;

  char* ws = (char*)d_ws;
  bf16* xb = (bf16*)(ws + (size_t)0);             // 8 MB  [4096][1024]
  bf16* wt = (bf16*)(ws + ((size_t)8 << 20));     // 8 MB  [4096][1024] transposed weights
  bf16* qb = (bf16*)(ws + ((size_t)16 << 20));    // 8 MB  token-major
  bf16* kb = (bf16*)(ws + ((size_t)24 << 20));    // 8 MB  token-major
  bf16* vtb = (bf16*)(ws + ((size_t)32 << 20));   // 8 MB  [b][h][d][s]
  bf16* ob = (bf16*)(ws + ((size_t)40 << 20));    // 8 MB  token-major
  unsigned long long* mbits = (unsigned long long*)(ws + ((size_t)48 << 20));  // 1 MB

  cast_x_kernel<<<4096, 256, 0, stream>>>(x, xb);
  transpose_w_kernel<<<dim3(128, 32), 256, 0, stream>>>(wq, wk, wv, wo, wt);
  pack_mask_kernel<<<32768, 256, 0, stream>>>(mask, mbits);
  gemm_bt<0><<<dim3(24, 32), 256, 0, stream>>>(xb, wt, bq, bk, bv, qb, kb, vtb, nullptr);
  attn_kernel<<<dim3(16, NH, BATCH), 256, 0, stream>>>(qb, kb, vtb, mbits, ob);
  gemm_bt<1><<<dim3(8, 32), 256, 0, stream>>>(ob, wt + (size_t)3072 * 1024, bo, nullptr, nullptr,
                                              nullptr, nullptr, nullptr, out);
}